// Round 22
// baseline (117.344 us; speedup 1.0000x reference)
//
#include <hip/hip_runtime.h>
#include <hip/hip_bf16.h>
#include <math.h>

#define BB 64
#define NN 1024
#define EPSV 1e-5f

typedef unsigned short u16;
typedef __attribute__((ext_vector_type(8))) short short8;
typedef __attribute__((ext_vector_type(4))) float f32x4;

#define GLOBAL_AS __attribute__((address_space(1)))
#define LDS_AS __attribute__((address_space(3)))

// sqrt(log2(e)): pre-scaling phi/eta so adj = exp2(-(dp^2+de^2)) directly.
#define SCL 1.20112240878645f

static __device__ __forceinline__ void gload_lds16(const void* g, void* l) {
  __builtin_amdgcn_global_load_lds((const GLOBAL_AS unsigned int*)g,
                                   (LDS_AS unsigned int*)l, 16, 0, 0);
}

static __device__ __forceinline__ u16 f2bf(float f) {
  __hip_bfloat16 h = __float2bfloat16(f);   // RNE
  union { __hip_bfloat16 h; u16 s; } u; u.h = h; return u.s;
}
static __device__ __forceinline__ float bf2f(u16 s) {
  unsigned int u = ((unsigned int)s) << 16;
  union { unsigned int u; float f; } c; c.u = u; return c.f;
}
static __device__ __forceinline__ float expn2(float dp, float de) {
#if __has_builtin(__builtin_amdgcn_exp2f)
  return __builtin_amdgcn_exp2f(fmaf(-dp, dp, -(de * de)));
#else
  return exp2f(fmaf(-dp, dp, -(de * de)));
#endif
}

// counted vmcnt wait (in-order VMEM retirement: <=N outstanding => older done)
template<int N>
static __device__ __forceinline__ void wait_vm() {
  static_assert(N == 0 || N == 1 || N == 2 || N == 4, "");
  if constexpr (N == 0) asm volatile("s_waitcnt vmcnt(0)" ::: "memory");
  if constexpr (N == 1) asm volatile("s_waitcnt vmcnt(1)" ::: "memory");
  if constexpr (N == 2) asm volatile("s_waitcnt vmcnt(2)" ::: "memory");
  if constexpr (N == 4) asm volatile("s_waitcnt vmcnt(4)" ::: "memory");
}

// XCD-aware bijective remap of the 1024-block 1D grid: each batch's 16
// blocks land on ONE XCD, so the batch's XT slab stays in that XCD's L2.
static __device__ __forceinline__ void remap(int L, int& b, int& bx) {
  b = (L & 7) * 8 + (L >> 7);
  bx = (L >> 3) & 15;
}

// ---------------------------------------------------------------------------
// fused0: batch-normalize + rank-2 layer 0 (wave = n-quarter, lane = m-row,
// broadcast LDS reads).  Writes XN1 (B,N,32) node-major and XT1 slab-ready
// (B,N/8,32,8).  Also converts W1/W2 to bf16 and zeroes the per-batch
// completion counters used by fused_last's folded final reduction.
// ---------------------------------------------------------------------------
__global__ __launch_bounds__(256, 4) void fused0_kernel(
    const float* __restrict__ e,
    const float* __restrict__ phi, const float* __restrict__ eta,
    const float* __restrict__ W0, const float* __restrict__ b0,
    const float* __restrict__ W1, const float* __restrict__ W2,
    u16* __restrict__ Wp1, u16* __restrict__ Wp2,
    int* __restrict__ cnt,          // (B) completion counters (zeroed here)
    u16* __restrict__ ZN,           // (B,N,32)
    u16* __restrict__ XT)           // (B,N/8,32,8)
{
  __shared__ float x0[NN];
  __shared__ float2 pe[NN];
  __shared__ float red[256];
  __shared__ u16 zt[64 * 40];

  int b, bx;
  remap(blockIdx.x, b, bx);
  int m0 = bx * 64;
  int tid = threadIdx.x;

  if (bx == 0 && tid == 0) cnt[b] = 0;
  if (bx == 0 && b == 0)
    for (int i = tid; i < 64 * 64; i += 256) Wp1[i] = f2bf(W1[i]);
  if (bx == 0 && b == 1)
    for (int i = tid; i < 64 * 128; i += 256) Wp2[i] = f2bf(W2[i]);

  const float* er = e + (size_t)b * NN;
  const float* phb = phi + (size_t)b * NN;
  const float* etb = eta + (size_t)b * NN;

  float s = 0.f;
  for (int i = tid; i < NN; i += 256) {
    float v = er[i]; x0[i] = v; s += v;
    pe[i] = make_float2(phb[i] * SCL, etb[i] * SCL);
  }
  red[tid] = s; __syncthreads();
  for (int off = 128; off > 0; off >>= 1) {
    if (tid < off) red[tid] += red[tid + off];
    __syncthreads();
  }
  float mu = red[0] * (1.f / NN);
  __syncthreads();
  float s2 = 0.f;
  for (int i = tid; i < NN; i += 256) { float d = x0[i] - mu; s2 += d * d; }
  red[tid] = s2; __syncthreads();
  for (int off = 128; off > 0; off >>= 1) {
    if (tid < off) red[tid] += red[tid + off];
    __syncthreads();
  }
  float sd = sqrtf(red[0] * (1.f / NN));
  float inv = 1.f / (sd + EPSV);
  for (int i = tid; i < NN; i += 256) x0[i] = (x0[i] - mu) * inv;
  __syncthreads();

  int q = tid >> 6;                 // wave = n-quarter
  int mi = tid & 63;                // m index
  int m = m0 + mi;
  float phm = pe[m].x, etm = pe[m].y;

  const float2* pp = &pe[q * 256];  // broadcast reads
  const float* xx = &x0[q * 256];
  float t0a = 0.f, t0b = 0.f;
#pragma unroll 4
  for (int n = 0; n < 256; n += 2) {
    float2 qa = pp[n], qb = pp[n + 1];
    float dpa = qa.x - phm, dea = qa.y - etm;
    float dpb = qb.x - phm, deb = qb.y - etm;
    t0a = fmaf(expn2(dpa, dea), xx[n], t0a);
    t0b = fmaf(expn2(dpb, deb), xx[n + 1], t0b);
  }
  red[q * 64 + mi] = t0a + t0b;
  __syncthreads();
  float t0 = (red[0 * 64 + mi] + red[1 * 64 + mi]) +
             (red[2 * 64 + mi] + red[3 * 64 + mi]);

  float x0m = x0[m];
  union { short8 v; u16 h[8]; } zrow;
#pragma unroll
  for (int oj = 0; oj < 8; ++oj) {
    int o = q * 8 + oj;
    float z = fmaf(W0[o * 2], x0m, fmaf(W0[o * 2 + 1], t0, b0[o]));
    zrow.h[oj] = f2bf(fmaxf(z, 0.f));
  }
  *(short8*)&ZN[((size_t)b * NN + m) * 32 + q * 8] = zrow.v;
  *(short8*)&zt[mi * 40 + q * 8] = zrow.v;
  __syncthreads();
  size_t basew = ((size_t)b * (NN / 8) + (m0 >> 3)) * (size_t)(32 * 8);
  for (int flat = tid; flat < 64 * 32; flat += 256) {
    int mo = flat >> 8;
    int o  = (flat >> 3) & 31;
    int m8 = flat & 7;
    XT[basew + flat] = zt[(mo * 8 + m8) * 40 + o];
  }
}

// ---------------------------------------------------------------------------
// fused layer (L1/L2): gather K-loop — NT-node double-buffered counted-vmcnt
// pipeline; adj A-fragments for step s generated BEFORE the barrier (pe-only
// dependency) so the post-wait region is pure ds_read+MFMA.  Then projection.
// NT=256 for CE=32 (LDS 40960 exactly), NT=128 for CE=64.
// ---------------------------------------------------------------------------
template<int CE, int O, int NT>
__global__ __launch_bounds__(256, 4) void fused_kernel(
    const u16* __restrict__ XT,     // (B,N/8,CE,8) bf16
    const u16* __restrict__ XN,     // (B,N,CE) bf16
    const float* __restrict__ phi,  // (B,N)
    const float* __restrict__ eta,  // (B,N)
    const u16* __restrict__ Wp,     // (O,2CE) bf16
    const float* __restrict__ bias, // (O)
    u16* __restrict__ ZN,           // (B,N,O)
    u16* __restrict__ XTo)          // (B,N/8,O,8)
{
  constexpr int NCT = CE / 16;
  constexpr int SLAB = NT * CE;          // elems per slab
  constexpr int SLABV = SLAB / 8;        // 16B vectors per slab
  constexpr int LPT = SLABV / 256;       // loads/thread/slab: 4 for both cfgs
  constexpr int KW = 2 * CE;
  constexpr int S = KW + 8;
  constexpr int OT = O / 16;
  constexpr int KS = KW / 32;
  constexpr int STEPS = NN / NT;         // 4 (CE=32) or 8 (CE=64)
  constexpr int KCN = NT / 32;           // 8 (CE=32) or 4 (CE=64)

  constexpr int PH1 = (int)sizeof(float2) * NN + 2 * SLAB * 2;
  constexpr int PH2 = 64 * S * 2;
  constexpr int ZTS = 64 * (O + 8) * 2;
  constexpr int SM0 = PH1 > PH2 ? PH1 : PH2;
  constexpr int SM = SM0 > ZTS ? SM0 : ZTS;
  __shared__ __align__(16) char smem[SM];
  float2* pe = (float2*)smem;
  u16* slabB = (u16*)(smem + sizeof(float2) * NN);
  u16* cat = (u16*)smem;
  u16* zt  = (u16*)smem;

  int b, bx;
  remap(blockIdx.x, b, bx);
  int m0 = bx * 64;
  int tid = threadIdx.x;
  int lane = tid & 63, w = tid >> 6, g = lane >> 4, cl = lane & 15;

  const float* phb = phi + (size_t)b * NN;
  const float* etb = eta + (size_t)b * NN;
  for (int i = tid; i < NN; i += 256)
    pe[i] = make_float2(phb[i] * SCL, etb[i] * SCL);

  int m_lane = m0 + w * 16 + cl;
  float phm = phb[m_lane] * SCL;
  float etm = etb[m_lane] * SCL;

  f32x4 acc[NCT];
#pragma unroll
  for (int ci = 0; ci < NCT; ++ci) acc[ci] = (f32x4){0.f, 0.f, 0.f, 0.f};

  const u16* xtb = XT + (size_t)b * NN * CE;   // batch base (slab-ready)

  auto stage = [&](int step, u16* dst) {
#pragma unroll
    for (int k = 0; k < LPT; ++k) {
      int v = tid + k * 256;
      int gg = v / CE, cc = v % CE;
      int cs = cc ^ (gg & 7);                   // bank swizzle (source side)
      gload_lds16(xtb + ((size_t)((step * NT >> 3) + gg) * CE + cs) * 8,
                  dst + v * 8);
    }
  };

  stage(0, slabB);                 // prefetch first slab
  __syncthreads();                 // pe fully written (needed by af-gen below)

  for (int s = 0; s < STEPS; ++s) {
    // --- pre-barrier: generate this step's adj fragments (pe-only) ---
    union { short8 v[KCN]; u16 h[KCN][8]; } af;
#pragma unroll
    for (int kc = 0; kc < KCN; ++kc) {
      const float2* pp = &pe[s * NT + kc * 32 + 8 * g];
#pragma unroll
      for (int j = 0; j < 8; ++j) {
        float2 qq = pp[j];
        af.h[kc][j] = f2bf(expn2(qq.x - phm, qq.y - etm));
      }
    }
    __builtin_amdgcn_sched_barrier(0);
    __builtin_amdgcn_s_barrier();  // compute(s-1) done with buf (s+1)&1
    __builtin_amdgcn_sched_barrier(0);
    if (s + 1 < STEPS) {
      stage(s + 1, slabB + ((s + 1) & 1) * SLAB);
      wait_vm<LPT>();              // stage(s) landed (only s+1's loads remain)
    } else {
      wait_vm<0>();
    }
    __builtin_amdgcn_sched_barrier(0);

    const u16* cur = slabB + (s & 1) * SLAB;
#pragma unroll
    for (int kc = 0; kc < KCN; ++kc) {
      int ggr = kc * 4 + g, sw = ggr & 7;
#pragma unroll
      for (int ci = 0; ci < NCT; ++ci) {
        const short8* bp =
            (const short8*)&cur[(ggr * CE + ((ci * 16 + cl) ^ sw)) * 8];
        acc[ci] = __builtin_amdgcn_mfma_f32_16x16x32_bf16(af.v[kc], *bp, acc[ci], 0, 0, 0);
      }
    }
  }
  __syncthreads();                 // all waves done with pe/slab before overlay

  // ---- phase 2: projection ----
  constexpr int CV = CE / 8;
  constexpr int NXN = (64 * CV + 255) / 256;
  constexpr bool XFULL = (64 * CV) % 256 == 0;
  short8 xnr[NXN];
#pragma unroll
  for (int i = 0; i < NXN; ++i) {
    int v = tid + i * 256;
    if (XFULL || v < 64 * CV) {
      int m = v / CV, cv = v % CV;
      xnr[i] = *(const short8*)&XN[((size_t)b * NN + m0 + m) * CE + cv * 8];
    }
  }
  float bz[OT];
#pragma unroll
  for (int oi = 0; oi < OT; ++oi) bz[oi] = bias[oi * 16 + cl];

#pragma unroll
  for (int ci = 0; ci < NCT; ++ci)
#pragma unroll
    for (int r = 0; r < 4; ++r) {
      int m = w * 16 + g * 4 + r;
      cat[m * S + CE + ci * 16 + cl] = f2bf(acc[ci][r]);
    }
#pragma unroll
  for (int i = 0; i < NXN; ++i) {
    int v = tid + i * 256;
    if (XFULL || v < 64 * CV) {
      int m = v / CV, cv = v % CV;
      *(short8*)&cat[m * S + cv * 8] = xnr[i];
    }
  }
  __syncthreads();

  short8 afp[KS];
#pragma unroll
  for (int kk = 0; kk < KS; ++kk)
    afp[kk] = *(const short8*)&cat[(w * 16 + cl) * S + kk * 32 + g * 8];

  constexpr int OB = (8 / KS) < OT ? (8 / KS) : OT;
  f32x4 pacc[OT];
#pragma unroll
  for (int oi = 0; oi < OT; ++oi) pacc[oi] = (f32x4){0.f, 0.f, 0.f, 0.f};
#pragma unroll
  for (int ob = 0; ob < OT; ob += OB) {
    short8 wfr[OB][KS];
#pragma unroll
    for (int oi = 0; oi < OB; ++oi)
#pragma unroll
      for (int kk = 0; kk < KS; ++kk)
        wfr[oi][kk] = *(const short8*)&Wp[((ob + oi) * 16 + cl) * KW + kk * 32 + g * 8];
#pragma unroll
    for (int oi = 0; oi < OB; ++oi)
#pragma unroll
      for (int kk = 0; kk < KS; ++kk)
        pacc[ob + oi] = __builtin_amdgcn_mfma_f32_16x16x32_bf16(
            afp[kk], wfr[oi][kk], pacc[ob + oi], 0, 0, 0);
  }
  __syncthreads();

#pragma unroll
  for (int oi = 0; oi < OT; ++oi) {
#pragma unroll
    for (int r = 0; r < 4; ++r) {
      float z = fmaxf(pacc[oi][r] + bz[oi], 0.f);
      u16 zb = f2bf(z);
      int m = w * 16 + 4 * g + r;
      ZN[((size_t)b * NN + m0 + m) * O + oi * 16 + cl] = zb;
      zt[m * (O + 8) + oi * 16 + cl] = zb;
    }
  }
  __syncthreads();
  size_t basew = ((size_t)b * (NN / 8) + (m0 >> 3)) * (size_t)(O * 8);
  for (int flat = tid; flat < 64 * O; flat += 256) {
    int mo = flat / (O * 8);
    int o  = (flat >> 3) % O;
    int m8 = flat & 7;
    XTo[basew + flat] = zt[(mo * 8 + m8) * (O + 8) + o];
  }
}

// ---------------------------------------------------------------------------
// fused last layer: NT=128 pipeline with pre-barrier af-gen + W3 dot +
// per-batch last-block final reduction (tree order identical to the old
// final_kernel's shfl_down tree) + sigmoid.  One fewer kernel launch.
// ---------------------------------------------------------------------------
__global__ __launch_bounds__(256, 4) void fused_last_kernel(
    const u16* __restrict__ XT,     // (B,N/8,64,8)
    const u16* __restrict__ XN,     // (B,N,64)
    const float* __restrict__ phi,
    const float* __restrict__ eta,
    const float* __restrict__ W3,   // (1,128) fp32
    const float* __restrict__ b3,
    float* __restrict__ partial,    // (B,16)
    int* __restrict__ cnt,          // (B) zeroed by fused0
    float* __restrict__ out)        // (B)
{
  constexpr int CE = 64, NCT = 4, NT = 128;
  constexpr int SLAB = NT * CE;
  constexpr int SLABV = SLAB / 8;
  constexpr int LPT = SLABV / 256;       // 4
  constexpr int S = 136;
  constexpr int STEPS = NN / NT;         // 8
  constexpr int KCN = NT / 32;           // 4

  constexpr int PH1 = (int)sizeof(float2) * NN + 2 * SLAB * 2;  // 40960
  __shared__ __align__(16) char smem[PH1];
  float2* pe = (float2*)smem;
  u16* slabB = (u16*)(smem + sizeof(float2) * NN);
  u16* cat = (u16*)smem;
  float* sW = (float*)(smem + 17408);
  float* red = (float*)(smem + 17408 + 512);

  int b, bx;
  remap(blockIdx.x, b, bx);
  int m0 = bx * 64;
  int tid = threadIdx.x;
  int lane = tid & 63, w = tid >> 6, g = lane >> 4, cl = lane & 15;

  const float* phb = phi + (size_t)b * NN;
  const float* etb = eta + (size_t)b * NN;
  for (int i = tid; i < NN; i += 256)
    pe[i] = make_float2(phb[i] * SCL, etb[i] * SCL);

  int m_lane = m0 + w * 16 + cl;
  float phm = phb[m_lane] * SCL;
  float etm = etb[m_lane] * SCL;

  f32x4 acc[NCT];
#pragma unroll
  for (int ci = 0; ci < NCT; ++ci) acc[ci] = (f32x4){0.f, 0.f, 0.f, 0.f};

  const u16* xtb = XT + (size_t)b * NN * CE;

  auto stage = [&](int step, u16* dst) {
#pragma unroll
    for (int k = 0; k < LPT; ++k) {
      int v = tid + k * 256;
      int gg = v / CE, cc = v % CE;
      int cs = cc ^ (gg & 7);
      gload_lds16(xtb + ((size_t)((step * NT >> 3) + gg) * CE + cs) * 8,
                  dst + v * 8);
    }
  };

  stage(0, slabB);
  __syncthreads();                 // pe fully written

  for (int s = 0; s < STEPS; ++s) {
    union { short8 v[KCN]; u16 h[KCN][8]; } af;
#pragma unroll
    for (int kc = 0; kc < KCN; ++kc) {
      const float2* pp = &pe[s * NT + kc * 32 + 8 * g];
#pragma unroll
      for (int j = 0; j < 8; ++j) {
        float2 qq = pp[j];
        af.h[kc][j] = f2bf(expn2(qq.x - phm, qq.y - etm));
      }
    }
    __builtin_amdgcn_sched_barrier(0);
    __builtin_amdgcn_s_barrier();
    __builtin_amdgcn_sched_barrier(0);
    if (s + 1 < STEPS) {
      stage(s + 1, slabB + ((s + 1) & 1) * SLAB);
      wait_vm<LPT>();
    } else {
      wait_vm<0>();
    }
    __builtin_amdgcn_sched_barrier(0);

    const u16* cur = slabB + (s & 1) * SLAB;
#pragma unroll
    for (int kc = 0; kc < KCN; ++kc) {
      int ggr = kc * 4 + g, sw = ggr & 7;
#pragma unroll
      for (int ci = 0; ci < NCT; ++ci) {
        const short8* bp =
            (const short8*)&cur[(ggr * CE + ((ci * 16 + cl) ^ sw)) * 8];
        acc[ci] = __builtin_amdgcn_mfma_f32_16x16x32_bf16(af.v[kc], *bp, acc[ci], 0, 0, 0);
      }
    }
  }
  __syncthreads();

  // ---- phase 2: z[m] = W3 . cat[m]; partial = sum_m z[m] ----
  short8 xnr0, xnr1;
  {
    int v0 = tid, v1 = tid + 256;
    int ma = v0 >> 3, ca = v0 & 7, mb = v1 >> 3, cb = v1 & 7;
    xnr0 = *(const short8*)&XN[((size_t)b * NN + m0 + ma) * CE + ca * 8];
    xnr1 = *(const short8*)&XN[((size_t)b * NN + m0 + mb) * CE + cb * 8];
  }
  if (tid < 128) sW[tid] = W3[tid];
#pragma unroll
  for (int ci = 0; ci < NCT; ++ci)
#pragma unroll
    for (int r = 0; r < 4; ++r) {
      int m = w * 16 + g * 4 + r;
      cat[m * S + CE + ci * 16 + cl] = f2bf(acc[ci][r]);
    }
  {
    int v0 = tid, v1 = tid + 256;
    int ma = v0 >> 3, ca = v0 & 7, mb = v1 >> 3, cb = v1 & 7;
    *(short8*)&cat[ma * S + ca * 8] = xnr0;
    *(short8*)&cat[mb * S + cb * 8] = xnr1;
  }
  __syncthreads();

  int m = tid & 63, q = tid >> 6;
  float sacc = 0.f;
#pragma unroll
  for (int v = 0; v < 4; ++v) {
    short8 cv = *(const short8*)&cat[m * S + q * 32 + v * 8];
#pragma unroll
    for (int j = 0; j < 8; ++j)
      sacc = fmaf(sW[q * 32 + v * 8 + j], bf2f((u16)cv[j]), sacc);
  }
  red[tid] = sacc; __syncthreads();
  for (int off = 128; off > 0; off >>= 1) {
    if (tid < off) red[tid] += red[tid + off];
    __syncthreads();
  }
  if (tid == 0) {
    partial[b * 16 + bx] = red[0] + 64.f * b3[0];
    __threadfence();                          // partial visible before count
    int old = atomicAdd(&cnt[b], 1);
    if (old == 15) {                          // last block for this batch
      __threadfence();
      float arr[16];
#pragma unroll
      for (int i = 0; i < 16; ++i) arr[i] = partial[b * 16 + i];
#pragma unroll
      for (int off = 8; off > 0; off >>= 1)   // same tree as old shfl_down
        for (int i = 0; i < off; ++i) arr[i] += arr[i + off];
      out[b] = 1.f / (1.f + __expf(-(arr[0] * (1.f / NN))));
    }
  }
}

// ---------------------------------------------------------------------------
extern "C" void kernel_launch(void* const* d_in, const int* in_sizes, int n_in,
                              void* d_out, int out_size, void* d_ws, size_t ws_size,
                              hipStream_t stream) {
  const float* e   = (const float*)d_in[0];
  const float* phi = (const float*)d_in[1];
  const float* eta = (const float*)d_in[2];
  const float* W0  = (const float*)d_in[3];
  const float* b0  = (const float*)d_in[4];
  const float* W1  = (const float*)d_in[5];
  const float* b1  = (const float*)d_in[6];
  const float* W2  = (const float*)d_in[7];
  const float* b2  = (const float*)d_in[8];
  const float* W3  = (const float*)d_in[9];
  const float* b3  = (const float*)d_in[10];

  // ws layout (no overlaps):
  //  [0, 4M)  PB partials (B*16 f32) @0; CNT (B ints) @64K
  //  [ 4, 8M) XT1 (B,N/8,32,8)   [ 8,12M) XN1 (B,N,32)
  //  [12,20M) XT2 (B,N/8,64,8)   [20,28M) XN2 (B,N,64)
  //  [28,36M) XT3 (B,N/8,64,8)   [36,44M) XN3 (B,N,64)
  //  [44M..)  Wp1 (64x64), Wp2 (64x128) bf16
  char* wsb = (char*)d_ws;
  const size_t MB = 1u << 20;
  float* PB  = (float*)(wsb);
  int*   CNT = (int*)(wsb + 64 * 1024);
  u16* XT1 = (u16*)(wsb + 4 * MB);
  u16* XN1 = (u16*)(wsb + 8 * MB);
  u16* XT2 = (u16*)(wsb + 12 * MB);
  u16* XN2 = (u16*)(wsb + 20 * MB);
  u16* XT3 = (u16*)(wsb + 28 * MB);
  u16* XN3 = (u16*)(wsb + 36 * MB);
  u16* Wp1 = (u16*)(wsb + 44 * MB);
  u16* Wp2 = Wp1 + 64 * 64;

  dim3 blk(256);
  dim3 gg(1024);   // 1D grid; XCD-aware remap inside kernels

  fused0_kernel<<<gg, blk, 0, stream>>>(e, phi, eta, W0, b0, W1, W2,
                                        Wp1, Wp2, CNT, XN1, XT1);
  fused_kernel<32, 64, 256><<<gg, blk, 0, stream>>>(XT1, XN1, phi, eta, Wp1, b1, XN2, XT2);
  fused_kernel<64, 64, 128><<<gg, blk, 0, stream>>>(XT2, XN2, phi, eta, Wp2, b2, XN3, XT3);
  fused_last_kernel<<<gg, blk, 0, stream>>>(XT3, XN3, phi, eta, W3, b3,
                                            PB, CNT, (float*)d_out);
}

// Round 23
// 93.592 us; speedup vs baseline: 1.2538x; 1.2538x over previous
//
#include <hip/hip_runtime.h>
#include <hip/hip_bf16.h>
#include <math.h>

#define BB 64
#define NN 1024
#define EPSV 1e-5f

typedef unsigned short u16;
typedef __attribute__((ext_vector_type(8))) short short8;
typedef __attribute__((ext_vector_type(4))) float f32x4;

#define GLOBAL_AS __attribute__((address_space(1)))
#define LDS_AS __attribute__((address_space(3)))

// sqrt(log2(e)): pre-scaling phi/eta so adj = exp2(-(dp^2+de^2)) directly.
#define SCL 1.20112240878645f

static __device__ __forceinline__ void gload_lds16(const void* g, void* l) {
  __builtin_amdgcn_global_load_lds((const GLOBAL_AS unsigned int*)g,
                                   (LDS_AS unsigned int*)l, 16, 0, 0);
}

static __device__ __forceinline__ u16 f2bf(float f) {
  __hip_bfloat16 h = __float2bfloat16(f);   // RNE
  union { __hip_bfloat16 h; u16 s; } u; u.h = h; return u.s;
}
static __device__ __forceinline__ float bf2f(u16 s) {
  unsigned int u = ((unsigned int)s) << 16;
  union { unsigned int u; float f; } c; c.u = u; return c.f;
}
static __device__ __forceinline__ float expn2(float dp, float de) {
#if __has_builtin(__builtin_amdgcn_exp2f)
  return __builtin_amdgcn_exp2f(fmaf(-dp, dp, -(de * de)));
#else
  return exp2f(fmaf(-dp, dp, -(de * de)));
#endif
}

// counted vmcnt wait (in-order VMEM retirement: <=N outstanding => older done)
template<int N>
static __device__ __forceinline__ void wait_vm() {
  static_assert(N == 0 || N == 1 || N == 2 || N == 4, "");
  if constexpr (N == 0) asm volatile("s_waitcnt vmcnt(0)" ::: "memory");
  if constexpr (N == 1) asm volatile("s_waitcnt vmcnt(1)" ::: "memory");
  if constexpr (N == 2) asm volatile("s_waitcnt vmcnt(2)" ::: "memory");
  if constexpr (N == 4) asm volatile("s_waitcnt vmcnt(4)" ::: "memory");
}

// XCD-aware bijective remap of the 1024-block 1D grid: each batch's 16
// blocks land on ONE XCD, so the batch's XT slab stays in that XCD's L2.
static __device__ __forceinline__ void remap(int L, int& b, int& bx) {
  b = (L & 7) * 8 + (L >> 7);
  bx = (L >> 3) & 15;
}

// ---------------------------------------------------------------------------
// fused0: batch-normalize + rank-2 layer 0 (wave = n-quarter, lane = m-row,
// broadcast LDS reads).  Writes XN1 (B,N,32) node-major and XT1 slab-ready
// (B,N/8,32,8).  Also converts W1/W2 to bf16.
// ---------------------------------------------------------------------------
__global__ __launch_bounds__(256, 4) void fused0_kernel(
    const float* __restrict__ e,
    const float* __restrict__ phi, const float* __restrict__ eta,
    const float* __restrict__ W0, const float* __restrict__ b0,
    const float* __restrict__ W1, const float* __restrict__ W2,
    u16* __restrict__ Wp1, u16* __restrict__ Wp2,
    u16* __restrict__ ZN,           // (B,N,32)
    u16* __restrict__ XT)           // (B,N/8,32,8)
{
  __shared__ float x0[NN];
  __shared__ float2 pe[NN];
  __shared__ float red[256];
  __shared__ u16 zt[64 * 40];

  int b, bx;
  remap(blockIdx.x, b, bx);
  int m0 = bx * 64;
  int tid = threadIdx.x;

  if (bx == 0 && b == 0)
    for (int i = tid; i < 64 * 64; i += 256) Wp1[i] = f2bf(W1[i]);
  if (bx == 0 && b == 1)
    for (int i = tid; i < 64 * 128; i += 256) Wp2[i] = f2bf(W2[i]);

  const float* er = e + (size_t)b * NN;
  const float* phb = phi + (size_t)b * NN;
  const float* etb = eta + (size_t)b * NN;

  float s = 0.f;
  for (int i = tid; i < NN; i += 256) {
    float v = er[i]; x0[i] = v; s += v;
    pe[i] = make_float2(phb[i] * SCL, etb[i] * SCL);
  }
  red[tid] = s; __syncthreads();
  for (int off = 128; off > 0; off >>= 1) {
    if (tid < off) red[tid] += red[tid + off];
    __syncthreads();
  }
  float mu = red[0] * (1.f / NN);
  __syncthreads();
  float s2 = 0.f;
  for (int i = tid; i < NN; i += 256) { float d = x0[i] - mu; s2 += d * d; }
  red[tid] = s2; __syncthreads();
  for (int off = 128; off > 0; off >>= 1) {
    if (tid < off) red[tid] += red[tid + off];
    __syncthreads();
  }
  float sd = sqrtf(red[0] * (1.f / NN));
  float inv = 1.f / (sd + EPSV);
  for (int i = tid; i < NN; i += 256) x0[i] = (x0[i] - mu) * inv;
  __syncthreads();

  int q = tid >> 6;                 // wave = n-quarter
  int mi = tid & 63;                // m index
  int m = m0 + mi;
  float phm = pe[m].x, etm = pe[m].y;

  const float2* pp = &pe[q * 256];  // broadcast reads
  const float* xx = &x0[q * 256];
  float t0a = 0.f, t0b = 0.f;
#pragma unroll 4
  for (int n = 0; n < 256; n += 2) {
    float2 qa = pp[n], qb = pp[n + 1];
    float dpa = qa.x - phm, dea = qa.y - etm;
    float dpb = qb.x - phm, deb = qb.y - etm;
    t0a = fmaf(expn2(dpa, dea), xx[n], t0a);
    t0b = fmaf(expn2(dpb, deb), xx[n + 1], t0b);
  }
  red[q * 64 + mi] = t0a + t0b;
  __syncthreads();
  float t0 = (red[0 * 64 + mi] + red[1 * 64 + mi]) +
             (red[2 * 64 + mi] + red[3 * 64 + mi]);

  float x0m = x0[m];
  union { short8 v; u16 h[8]; } zrow;
#pragma unroll
  for (int oj = 0; oj < 8; ++oj) {
    int o = q * 8 + oj;
    float z = fmaf(W0[o * 2], x0m, fmaf(W0[o * 2 + 1], t0, b0[o]));
    zrow.h[oj] = f2bf(fmaxf(z, 0.f));
  }
  *(short8*)&ZN[((size_t)b * NN + m) * 32 + q * 8] = zrow.v;
  *(short8*)&zt[mi * 40 + q * 8] = zrow.v;
  __syncthreads();
  size_t basew = ((size_t)b * (NN / 8) + (m0 >> 3)) * (size_t)(32 * 8);
  for (int flat = tid; flat < 64 * 32; flat += 256) {
    int mo = flat >> 8;
    int o  = (flat >> 3) & 31;
    int m8 = flat & 7;
    XT[basew + flat] = zt[(mo * 8 + m8) * 40 + o];
  }
}

// ---------------------------------------------------------------------------
// fused layer (L1/L2): gather K-loop — NT=128 double-buffered counted-vmcnt
// pipeline; adj A-fragments for step s generated BEFORE the barrier (pe-only
// dependency) so the post-wait region is pure ds_read+MFMA.  Then projection.
// ---------------------------------------------------------------------------
template<int CE, int O>
__global__ __launch_bounds__(256, 4) void fused_kernel(
    const u16* __restrict__ XT,     // (B,N/8,CE,8) bf16
    const u16* __restrict__ XN,     // (B,N,CE) bf16
    const float* __restrict__ phi,  // (B,N)
    const float* __restrict__ eta,  // (B,N)
    const u16* __restrict__ Wp,     // (O,2CE) bf16
    const float* __restrict__ bias, // (O)
    u16* __restrict__ ZN,           // (B,N,O)
    u16* __restrict__ XTo)          // (B,N/8,O,8)
{
  constexpr int NT = 128;
  constexpr int NCT = CE / 16;
  constexpr int SLAB = NT * CE;          // elems per slab
  constexpr int SLABV = SLAB / 8;        // 16B vectors per slab
  constexpr int LPT = SLABV / 256;       // loads/thread/slab: 2 (CE=32), 4 (CE=64)
  constexpr int KW = 2 * CE;
  constexpr int S = KW + 8;
  constexpr int OT = O / 16;
  constexpr int KS = KW / 32;
  constexpr int STEPS = NN / NT;         // 8
  constexpr int KCN = NT / 32;           // 4

  constexpr int PH1 = (int)sizeof(float2) * NN + 2 * SLAB * 2;
  constexpr int PH2 = 64 * S * 2;
  constexpr int ZTS = 64 * (O + 8) * 2;
  constexpr int SM0 = PH1 > PH2 ? PH1 : PH2;
  constexpr int SM = SM0 > ZTS ? SM0 : ZTS;
  __shared__ __align__(16) char smem[SM];
  float2* pe = (float2*)smem;
  u16* slabB = (u16*)(smem + sizeof(float2) * NN);
  u16* cat = (u16*)smem;
  u16* zt  = (u16*)smem;

  int b, bx;
  remap(blockIdx.x, b, bx);
  int m0 = bx * 64;
  int tid = threadIdx.x;
  int lane = tid & 63, w = tid >> 6, g = lane >> 4, cl = lane & 15;

  const float* phb = phi + (size_t)b * NN;
  const float* etb = eta + (size_t)b * NN;
  for (int i = tid; i < NN; i += 256)
    pe[i] = make_float2(phb[i] * SCL, etb[i] * SCL);

  int m_lane = m0 + w * 16 + cl;
  float phm = phb[m_lane] * SCL;
  float etm = etb[m_lane] * SCL;

  f32x4 acc[NCT];
#pragma unroll
  for (int ci = 0; ci < NCT; ++ci) acc[ci] = (f32x4){0.f, 0.f, 0.f, 0.f};

  const u16* xtb = XT + (size_t)b * NN * CE;   // batch base (slab-ready)

  auto stage = [&](int step, u16* dst) {
#pragma unroll
    for (int k = 0; k < LPT; ++k) {
      int v = tid + k * 256;
      int gg = v / CE, cc = v % CE;
      int cs = cc ^ (gg & 7);                   // bank swizzle (source side)
      gload_lds16(xtb + ((size_t)((step * NT >> 3) + gg) * CE + cs) * 8,
                  dst + v * 8);
    }
  };

  stage(0, slabB);                 // prefetch first slab
  __syncthreads();                 // pe fully written (needed by af-gen below)

  for (int s = 0; s < STEPS; ++s) {
    // --- pre-barrier: generate this step's adj fragments (pe-only) ---
    union { short8 v[KCN]; u16 h[KCN][8]; } af;
#pragma unroll
    for (int kc = 0; kc < KCN; ++kc) {
      const float2* pp = &pe[s * NT + kc * 32 + 8 * g];
#pragma unroll
      for (int j = 0; j < 8; ++j) {
        float2 qq = pp[j];
        af.h[kc][j] = f2bf(expn2(qq.x - phm, qq.y - etm));
      }
    }
    __builtin_amdgcn_sched_barrier(0);
    __builtin_amdgcn_s_barrier();  // compute(s-1) done with buf (s+1)&1
    __builtin_amdgcn_sched_barrier(0);
    if (s + 1 < STEPS) {
      stage(s + 1, slabB + ((s + 1) & 1) * SLAB);
      wait_vm<LPT>();              // stage(s) landed (only s+1's loads remain)
    } else {
      wait_vm<0>();
    }
    __builtin_amdgcn_sched_barrier(0);

    const u16* cur = slabB + (s & 1) * SLAB;
#pragma unroll
    for (int kc = 0; kc < KCN; ++kc) {
      int ggr = kc * 4 + g, sw = ggr & 7;
#pragma unroll
      for (int ci = 0; ci < NCT; ++ci) {
        const short8* bp =
            (const short8*)&cur[(ggr * CE + ((ci * 16 + cl) ^ sw)) * 8];
        acc[ci] = __builtin_amdgcn_mfma_f32_16x16x32_bf16(af.v[kc], *bp, acc[ci], 0, 0, 0);
      }
    }
  }
  __syncthreads();                 // all waves done with pe/slab before overlay

  // ---- phase 2: projection ----
  constexpr int CV = CE / 8;
  constexpr int NXN = (64 * CV + 255) / 256;
  constexpr bool XFULL = (64 * CV) % 256 == 0;
  short8 xnr[NXN];
#pragma unroll
  for (int i = 0; i < NXN; ++i) {
    int v = tid + i * 256;
    if (XFULL || v < 64 * CV) {
      int m = v / CV, cv = v % CV;
      xnr[i] = *(const short8*)&XN[((size_t)b * NN + m0 + m) * CE + cv * 8];
    }
  }
  float bz[OT];
#pragma unroll
  for (int oi = 0; oi < OT; ++oi) bz[oi] = bias[oi * 16 + cl];

#pragma unroll
  for (int ci = 0; ci < NCT; ++ci)
#pragma unroll
    for (int r = 0; r < 4; ++r) {
      int m = w * 16 + g * 4 + r;
      cat[m * S + CE + ci * 16 + cl] = f2bf(acc[ci][r]);
    }
#pragma unroll
  for (int i = 0; i < NXN; ++i) {
    int v = tid + i * 256;
    if (XFULL || v < 64 * CV) {
      int m = v / CV, cv = v % CV;
      *(short8*)&cat[m * S + cv * 8] = xnr[i];
    }
  }
  __syncthreads();

  short8 afp[KS];
#pragma unroll
  for (int kk = 0; kk < KS; ++kk)
    afp[kk] = *(const short8*)&cat[(w * 16 + cl) * S + kk * 32 + g * 8];

  constexpr int OB = (8 / KS) < OT ? (8 / KS) : OT;
  f32x4 pacc[OT];
#pragma unroll
  for (int oi = 0; oi < OT; ++oi) pacc[oi] = (f32x4){0.f, 0.f, 0.f, 0.f};
#pragma unroll
  for (int ob = 0; ob < OT; ob += OB) {
    short8 wfr[OB][KS];
#pragma unroll
    for (int oi = 0; oi < OB; ++oi)
#pragma unroll
      for (int kk = 0; kk < KS; ++kk)
        wfr[oi][kk] = *(const short8*)&Wp[((ob + oi) * 16 + cl) * KW + kk * 32 + g * 8];
#pragma unroll
    for (int oi = 0; oi < OB; ++oi)
#pragma unroll
      for (int kk = 0; kk < KS; ++kk)
        pacc[ob + oi] = __builtin_amdgcn_mfma_f32_16x16x32_bf16(
            afp[kk], wfr[oi][kk], pacc[ob + oi], 0, 0, 0);
  }
  __syncthreads();

#pragma unroll
  for (int oi = 0; oi < OT; ++oi) {
#pragma unroll
    for (int r = 0; r < 4; ++r) {
      float z = fmaxf(pacc[oi][r] + bz[oi], 0.f);
      u16 zb = f2bf(z);
      int m = w * 16 + 4 * g + r;
      ZN[((size_t)b * NN + m0 + m) * O + oi * 16 + cl] = zb;
      zt[m * (O + 8) + oi * 16 + cl] = zb;
    }
  }
  __syncthreads();
  size_t basew = ((size_t)b * (NN / 8) + (m0 >> 3)) * (size_t)(O * 8);
  for (int flat = tid; flat < 64 * O; flat += 256) {
    int mo = flat / (O * 8);
    int o  = (flat >> 3) % O;
    int m8 = flat & 7;
    XTo[basew + flat] = zt[(mo * 8 + m8) * (O + 8) + o];
  }
}

// ---------------------------------------------------------------------------
// fused last layer: same NT=128 pipeline with pre-barrier af-gen + W3 dot.
// ---------------------------------------------------------------------------
__global__ __launch_bounds__(256, 4) void fused_last_kernel(
    const u16* __restrict__ XT,     // (B,N/8,64,8)
    const u16* __restrict__ XN,     // (B,N,64)
    const float* __restrict__ phi,
    const float* __restrict__ eta,
    const float* __restrict__ W3,   // (1,128) fp32
    const float* __restrict__ b3,
    float* __restrict__ partial)    // (B,16)
{
  constexpr int CE = 64, NCT = 4, NT = 128;
  constexpr int SLAB = NT * CE;
  constexpr int SLABV = SLAB / 8;
  constexpr int LPT = SLABV / 256;       // 4
  constexpr int S = 136;
  constexpr int STEPS = NN / NT;         // 8
  constexpr int KCN = NT / 32;           // 4

  constexpr int PH1 = (int)sizeof(float2) * NN + 2 * SLAB * 2;  // 40960
  __shared__ __align__(16) char smem[PH1];
  float2* pe = (float2*)smem;
  u16* slabB = (u16*)(smem + sizeof(float2) * NN);
  u16* cat = (u16*)smem;
  float* sW = (float*)(smem + 17408);
  float* red = (float*)(smem + 17408 + 512);

  int b, bx;
  remap(blockIdx.x, b, bx);
  int m0 = bx * 64;
  int tid = threadIdx.x;
  int lane = tid & 63, w = tid >> 6, g = lane >> 4, cl = lane & 15;

  const float* phb = phi + (size_t)b * NN;
  const float* etb = eta + (size_t)b * NN;
  for (int i = tid; i < NN; i += 256)
    pe[i] = make_float2(phb[i] * SCL, etb[i] * SCL);

  int m_lane = m0 + w * 16 + cl;
  float phm = phb[m_lane] * SCL;
  float etm = etb[m_lane] * SCL;

  f32x4 acc[NCT];
#pragma unroll
  for (int ci = 0; ci < NCT; ++ci) acc[ci] = (f32x4){0.f, 0.f, 0.f, 0.f};

  const u16* xtb = XT + (size_t)b * NN * CE;

  auto stage = [&](int step, u16* dst) {
#pragma unroll
    for (int k = 0; k < LPT; ++k) {
      int v = tid + k * 256;
      int gg = v / CE, cc = v % CE;
      int cs = cc ^ (gg & 7);
      gload_lds16(xtb + ((size_t)((step * NT >> 3) + gg) * CE + cs) * 8,
                  dst + v * 8);
    }
  };

  stage(0, slabB);
  __syncthreads();                 // pe fully written

  for (int s = 0; s < STEPS; ++s) {
    union { short8 v[KCN]; u16 h[KCN][8]; } af;
#pragma unroll
    for (int kc = 0; kc < KCN; ++kc) {
      const float2* pp = &pe[s * NT + kc * 32 + 8 * g];
#pragma unroll
      for (int j = 0; j < 8; ++j) {
        float2 qq = pp[j];
        af.h[kc][j] = f2bf(expn2(qq.x - phm, qq.y - etm));
      }
    }
    __builtin_amdgcn_sched_barrier(0);
    __builtin_amdgcn_s_barrier();
    __builtin_amdgcn_sched_barrier(0);
    if (s + 1 < STEPS) {
      stage(s + 1, slabB + ((s + 1) & 1) * SLAB);
      wait_vm<LPT>();
    } else {
      wait_vm<0>();
    }
    __builtin_amdgcn_sched_barrier(0);

    const u16* cur = slabB + (s & 1) * SLAB;
#pragma unroll
    for (int kc = 0; kc < KCN; ++kc) {
      int ggr = kc * 4 + g, sw = ggr & 7;
#pragma unroll
      for (int ci = 0; ci < NCT; ++ci) {
        const short8* bp =
            (const short8*)&cur[(ggr * CE + ((ci * 16 + cl) ^ sw)) * 8];
        acc[ci] = __builtin_amdgcn_mfma_f32_16x16x32_bf16(af.v[kc], *bp, acc[ci], 0, 0, 0);
      }
    }
  }
  __syncthreads();

  // ---- phase 2: z[m] = W3 . cat[m]; partial = sum_m z[m] ----
  short8 xnr0, xnr1;
  {
    int v0 = tid, v1 = tid + 256;
    int ma = v0 >> 3, ca = v0 & 7, mb = v1 >> 3, cb = v1 & 7;
    xnr0 = *(const short8*)&XN[((size_t)b * NN + m0 + ma) * CE + ca * 8];
    xnr1 = *(const short8*)&XN[((size_t)b * NN + m0 + mb) * CE + cb * 8];
  }
  if (tid < 128) sW[tid] = W3[tid];
#pragma unroll
  for (int ci = 0; ci < NCT; ++ci)
#pragma unroll
    for (int r = 0; r < 4; ++r) {
      int m = w * 16 + g * 4 + r;
      cat[m * S + CE + ci * 16 + cl] = f2bf(acc[ci][r]);
    }
  {
    int v0 = tid, v1 = tid + 256;
    int ma = v0 >> 3, ca = v0 & 7, mb = v1 >> 3, cb = v1 & 7;
    *(short8*)&cat[ma * S + ca * 8] = xnr0;
    *(short8*)&cat[mb * S + cb * 8] = xnr1;
  }
  __syncthreads();

  int m = tid & 63, q = tid >> 6;
  float sacc = 0.f;
#pragma unroll
  for (int v = 0; v < 4; ++v) {
    short8 cv = *(const short8*)&cat[m * S + q * 32 + v * 8];
#pragma unroll
    for (int j = 0; j < 8; ++j)
      sacc = fmaf(sW[q * 32 + v * 8 + j], bf2f((u16)cv[j]), sacc);
  }
  red[tid] = sacc; __syncthreads();
  for (int off = 128; off > 0; off >>= 1) {
    if (tid < off) red[tid] += red[tid + off];
    __syncthreads();
  }
  if (tid == 0)
    partial[b * 16 + bx] = red[0] + 64.f * b3[0];
}

// ---------------------------------------------------------------------------
__global__ __launch_bounds__(64) void final_kernel(const float* __restrict__ partial,
                                                   float* __restrict__ out) {
  int b = blockIdx.x;
  int lane = threadIdx.x;
  float v = (lane < 16) ? partial[b * 16 + lane] : 0.f;
#pragma unroll
  for (int off = 8; off > 0; off >>= 1) v += __shfl_down(v, off);
  if (lane == 0) out[b] = 1.f / (1.f + __expf(-(v * (1.f / NN))));
}

// ---------------------------------------------------------------------------
extern "C" void kernel_launch(void* const* d_in, const int* in_sizes, int n_in,
                              void* d_out, int out_size, void* d_ws, size_t ws_size,
                              hipStream_t stream) {
  const float* e   = (const float*)d_in[0];
  const float* phi = (const float*)d_in[1];
  const float* eta = (const float*)d_in[2];
  const float* W0  = (const float*)d_in[3];
  const float* b0  = (const float*)d_in[4];
  const float* W1  = (const float*)d_in[5];
  const float* b1  = (const float*)d_in[6];
  const float* W2  = (const float*)d_in[7];
  const float* b2  = (const float*)d_in[8];
  const float* W3  = (const float*)d_in[9];
  const float* b3  = (const float*)d_in[10];

  // ws layout (no overlaps):
  //  [0, 4M)  PB partials
  //  [ 4, 8M) XT1 (B,N/8,32,8)   [ 8,12M) XN1 (B,N,32)
  //  [12,20M) XT2 (B,N/8,64,8)   [20,28M) XN2 (B,N,64)
  //  [28,36M) XT3 (B,N/8,64,8)   [36,44M) XN3 (B,N,64)
  //  [44M..)  Wp1 (64x64), Wp2 (64x128) bf16
  char* wsb = (char*)d_ws;
  const size_t MB = 1u << 20;
  float* PB = (float*)(wsb);
  u16* XT1 = (u16*)(wsb + 4 * MB);
  u16* XN1 = (u16*)(wsb + 8 * MB);
  u16* XT2 = (u16*)(wsb + 12 * MB);
  u16* XN2 = (u16*)(wsb + 20 * MB);
  u16* XT3 = (u16*)(wsb + 28 * MB);
  u16* XN3 = (u16*)(wsb + 36 * MB);
  u16* Wp1 = (u16*)(wsb + 44 * MB);
  u16* Wp2 = Wp1 + 64 * 64;

  dim3 blk(256);
  dim3 gg(1024);   // 1D grid; XCD-aware remap inside kernels

  fused0_kernel<<<gg, blk, 0, stream>>>(e, phi, eta, W0, b0, W1, W2,
                                        Wp1, Wp2, XN1, XT1);
  fused_kernel<32, 64><<<gg, blk, 0, stream>>>(XT1, XN1, phi, eta, Wp1, b1, XN2, XT2);
  fused_kernel<64, 64><<<gg, blk, 0, stream>>>(XT2, XN2, phi, eta, Wp2, b2, XN3, XT3);
  fused_last_kernel<<<gg, blk, 0, stream>>>(XT3, XN3, phi, eta, W3, b3, PB);

  final_kernel<<<BB, dim3(64), 0, stream>>>(PB, (float*)d_out);
}